// Round 1
// baseline (1054.829 us; speedup 1.0000x reference)
//
#include <hip/hip_runtime.h>
#include <hip/hip_bf16.h>
#include <stdint.h>

typedef unsigned short u16;
typedef __bf16 bf16x8 __attribute__((ext_vector_type(8)));
typedef float f32x4 __attribute__((ext_vector_type(4)));

#define BB 4
#define TT 2048
#define CC 1024
#define HH 16
#define DD 64

__device__ __forceinline__ u16 f2bf(float f) {
  union { float f; unsigned int u; } v; v.f = f;
  unsigned int u = v.u;
  unsigned int r = (u + 0x7fffu + ((u >> 16) & 1u)) >> 16;
  return (u16)r;
}

// ---------------- cast x -> bf16 ----------------
__global__ __launch_bounds__(256) void k_cast_x(const float* __restrict__ x,
                                                u16* __restrict__ xb) {
  int i = (blockIdx.x * 256 + threadIdx.x) * 4;
  float4 f = *reinterpret_cast<const float4*>(x + i);
  ushort4 o;
  o.x = f2bf(f.x); o.y = f2bf(f.y); o.z = f2bf(f.z); o.w = f2bf(f.w);
  *reinterpret_cast<ushort4*>(xb + i) = o;
}

// ------------- transpose + cast weights: wt[n][k] = w[k][n] -------------
__global__ __launch_bounds__(256) void k_transpose_w(
    const float* __restrict__ w0, const float* __restrict__ w1,
    const float* __restrict__ w2, const float* __restrict__ w3,
    u16* __restrict__ t0, u16* __restrict__ t1,
    u16* __restrict__ t2, u16* __restrict__ t3) {
  const float* w = blockIdx.z == 0 ? w0 : blockIdx.z == 1 ? w1 : blockIdx.z == 2 ? w2 : w3;
  u16* t = blockIdx.z == 0 ? t0 : blockIdx.z == 1 ? t1 : blockIdx.z == 2 ? t2 : t3;
  __shared__ u16 tile[32][33];
  int tx = threadIdx.x, ty = threadIdx.y;
  int k0 = blockIdx.x * 32, n0 = blockIdx.y * 32;
#pragma unroll
  for (int r = 0; r < 4; r++)
    tile[ty + r * 8][tx] = f2bf(w[(size_t)(k0 + ty + r * 8) * CC + n0 + tx]);
  __syncthreads();
#pragma unroll
  for (int r = 0; r < 4; r++)
    t[(size_t)(n0 + ty + r * 8) * CC + k0 + tx] = tile[tx][ty + r * 8];
}

// ---------------- fused QKV GEMM ----------------
// C[m,n] = sum_k X[m,k] * W[k,n] + bias[n],  W given transposed wt[n][k] (bf16)
// mat 0 -> q (bf16 ws), 1 -> k (fp32 out + bf16 ws), 2 -> v (fp32 out + bf16 ws)
// output layout (B,H,T,D): idx = ((b*H+h)*T + t)*D + d ; m=b*T+t, n=h*D+d
__global__ __launch_bounds__(256) void k_gemm_qkv(
    const u16* __restrict__ xb,
    const u16* __restrict__ wtq, const u16* __restrict__ wtk, const u16* __restrict__ wtv,
    const float* __restrict__ bq, const float* __restrict__ bk, const float* __restrict__ bv,
    u16* __restrict__ qb, u16* __restrict__ kb, u16* __restrict__ vb,
    float* __restrict__ out_k, float* __restrict__ out_v) {
  int mat = blockIdx.z;
  const u16* wt = mat == 0 ? wtq : mat == 1 ? wtk : wtv;
  const float* bias = mat == 0 ? bq : mat == 1 ? bk : bv;
  int tile_m = blockIdx.x * 64;
  int tile_n = blockIdx.y * 64;
  int lane = threadIdx.x & 63;
  int wave = threadIdx.x >> 6;
  int l15 = lane & 15, quad = lane >> 4;
  int arow = tile_m + wave * 16 + l15;

  f32x4 acc[4] = {};
  const u16* aptr = xb + (size_t)arow * CC + quad * 8;
  for (int k0 = 0; k0 < CC; k0 += 32) {
    bf16x8 af = *reinterpret_cast<const bf16x8*>(aptr + k0);
#pragma unroll
    for (int nb = 0; nb < 4; nb++) {
      int n = tile_n + nb * 16 + l15;
      bf16x8 bfrag = *reinterpret_cast<const bf16x8*>(wt + (size_t)n * CC + k0 + quad * 8);
      acc[nb] = __builtin_amdgcn_mfma_f32_16x16x32_bf16(af, bfrag, acc[nb], 0, 0, 0);
    }
  }

#pragma unroll
  for (int nb = 0; nb < 4; nb++) {
    int n = tile_n + nb * 16 + l15;
    int h = n >> 6, d = n & 63;
    float bias_n = bias[n];
#pragma unroll
    for (int r = 0; r < 4; r++) {
      int m = tile_m + wave * 16 + quad * 4 + r;
      int b = m >> 11, t = m & 2047;
      float val = acc[nb][r] + bias_n;
      size_t idx = (((size_t)(b * HH + h)) * TT + t) * DD + d;
      if (mat == 0) {
        qb[idx] = f2bf(val);
      } else if (mat == 1) {
        out_k[idx] = val;
        kb[idx] = f2bf(val);
      } else {
        out_v[idx] = val;
        vb[idx] = f2bf(val);
      }
    }
  }
}

// ---------------- flash attention (causal) ----------------
// grid: (T/64, B*H), block 256 (4 waves, 16 query rows per wave)
__global__ __launch_bounds__(256) void k_attn(
    const u16* __restrict__ qb, const u16* __restrict__ kbuf, const u16* __restrict__ vbuf,
    u16* __restrict__ yatt) {
  int qblk = blockIdx.x;
  int bh = blockIdx.y;
  int tid = threadIdx.x;
  int lane = tid & 63;
  int wave = tid >> 6;
  int l15 = lane & 15, quad = lane >> 4;

  const u16* Q = qb + (size_t)bh * TT * DD;
  const u16* K = kbuf + (size_t)bh * TT * DD;
  const u16* V = vbuf + (size_t)bh * TT * DD;

  __shared__ u16 vt[64][72];      // [d][key] transposed V tile
  __shared__ u16 pl[4][16][72];   // [wave][qrow][key] P tile

  int qr = qblk * 64 + wave * 16 + l15;
  bf16x8 qf0 = *reinterpret_cast<const bf16x8*>(Q + (size_t)qr * DD + quad * 8);
  bf16x8 qf1 = *reinterpret_cast<const bf16x8*>(Q + (size_t)qr * DD + 32 + quad * 8);

  f32x4 o_acc[4] = {};
  float m_run[4], l_run[4];
#pragma unroll
  for (int r = 0; r < 4; r++) { m_run[r] = -1e30f; l_run[r] = 0.f; }

  for (int kblk = 0; kblk <= qblk; kblk++) {
    __syncthreads();
    // stage V^T tile: vt[d][key] = V[kblk*64+key][d]
#pragma unroll
    for (int rep = 0; rep < 16; rep++) {
      int idx = rep * 256 + tid;
      int key = idx >> 6, d = idx & 63;
      vt[d][key] = V[(size_t)(kblk * 64 + key) * DD + d];
    }
    __syncthreads();

    // S = Q K^T (16 rows x 64 keys per wave)
    f32x4 s_acc[4];
#pragma unroll
    for (int nb = 0; nb < 4; nb++) {
      int key = kblk * 64 + nb * 16 + l15;
      bf16x8 kf0 = *reinterpret_cast<const bf16x8*>(K + (size_t)key * DD + quad * 8);
      bf16x8 kf1 = *reinterpret_cast<const bf16x8*>(K + (size_t)key * DD + 32 + quad * 8);
      f32x4 z = {};
      z = __builtin_amdgcn_mfma_f32_16x16x32_bf16(qf0, kf0, z, 0, 0, 0);
      z = __builtin_amdgcn_mfma_f32_16x16x32_bf16(qf1, kf1, z, 0, 0, 0);
      s_acc[nb] = z;
    }

    // mask + row max
    float p[4][4];   // [nb][r]
    float newm[4];
#pragma unroll
    for (int r = 0; r < 4; r++) {
      int qg = qblk * 64 + wave * 16 + quad * 4 + r;
      float mx = -1e30f;
#pragma unroll
      for (int nb = 0; nb < 4; nb++) {
        int kg = kblk * 64 + nb * 16 + l15;
        float s = s_acc[nb][r] * 0.125f;
        s = (kg <= qg) ? s : -1e30f;
        p[nb][r] = s;
        mx = fmaxf(mx, s);
      }
      newm[r] = mx;
    }
#pragma unroll
    for (int off = 1; off < 16; off <<= 1) {
#pragma unroll
      for (int r = 0; r < 4; r++)
        newm[r] = fmaxf(newm[r], __shfl_xor(newm[r], off, 64));
    }

    float alpha[4], rs[4];
#pragma unroll
    for (int r = 0; r < 4; r++) {
      float mnew = fmaxf(m_run[r], newm[r]);
      alpha[r] = __expf(m_run[r] - mnew);
      m_run[r] = mnew;
      float local = 0.f;
#pragma unroll
      for (int nb = 0; nb < 4; nb++) {
        float e = __expf(p[nb][r] - mnew);
        p[nb][r] = e;
        local += e;
      }
      rs[r] = local;
    }
#pragma unroll
    for (int off = 1; off < 16; off <<= 1) {
#pragma unroll
      for (int r = 0; r < 4; r++)
        rs[r] += __shfl_xor(rs[r], off, 64);
    }
#pragma unroll
    for (int r = 0; r < 4; r++) {
      l_run[r] = l_run[r] * alpha[r] + rs[r];
#pragma unroll
      for (int db = 0; db < 4; db++) o_acc[db][r] *= alpha[r];
    }

    // P -> LDS (C-layout -> row major)
#pragma unroll
    for (int nb = 0; nb < 4; nb++)
#pragma unroll
      for (int r = 0; r < 4; r++)
        pl[wave][quad * 4 + r][nb * 16 + l15] = f2bf(p[nb][r]);
    __syncthreads();

    // O += P V
#pragma unroll
    for (int half = 0; half < 2; half++) {
      bf16x8 pf = *reinterpret_cast<const bf16x8*>(&pl[wave][l15][half * 32 + quad * 8]);
#pragma unroll
      for (int db = 0; db < 4; db++) {
        bf16x8 vf = *reinterpret_cast<const bf16x8*>(&vt[db * 16 + l15][half * 32 + quad * 8]);
        o_acc[db] = __builtin_amdgcn_mfma_f32_16x16x32_bf16(pf, vf, o_acc[db], 0, 0, 0);
      }
    }
  }

  // epilogue: y_att[b][t][h*64+d] bf16
  int h = bh & 15, b = bh >> 4;
#pragma unroll
  for (int r = 0; r < 4; r++) {
    float inv = 1.0f / l_run[r];
    int tq = qblk * 64 + wave * 16 + quad * 4 + r;
#pragma unroll
    for (int db = 0; db < 4; db++) {
      int d = db * 16 + l15;
      yatt[((size_t)(b * TT + tq)) * CC + h * DD + d] = f2bf(o_acc[db][r] * inv);
    }
  }
}

// ---------------- output projection ----------------
__global__ __launch_bounds__(256) void k_gemm_proj(
    const u16* __restrict__ yb, const u16* __restrict__ wtp,
    const float* __restrict__ bp, float* __restrict__ out) {
  int tile_m = blockIdx.x * 64;
  int tile_n = blockIdx.y * 64;
  int lane = threadIdx.x & 63;
  int wave = threadIdx.x >> 6;
  int l15 = lane & 15, quad = lane >> 4;
  int arow = tile_m + wave * 16 + l15;

  f32x4 acc[4] = {};
  const u16* aptr = yb + (size_t)arow * CC + quad * 8;
  for (int k0 = 0; k0 < CC; k0 += 32) {
    bf16x8 af = *reinterpret_cast<const bf16x8*>(aptr + k0);
#pragma unroll
    for (int nb = 0; nb < 4; nb++) {
      int n = tile_n + nb * 16 + l15;
      bf16x8 bfrag = *reinterpret_cast<const bf16x8*>(wtp + (size_t)n * CC + k0 + quad * 8);
      acc[nb] = __builtin_amdgcn_mfma_f32_16x16x32_bf16(af, bfrag, acc[nb], 0, 0, 0);
    }
  }
#pragma unroll
  for (int nb = 0; nb < 4; nb++) {
    int n = tile_n + nb * 16 + l15;
    float bias_n = bp[n];
#pragma unroll
    for (int r = 0; r < 4; r++) {
      int m = tile_m + wave * 16 + quad * 4 + r;
      out[(size_t)m * CC + n] = acc[nb][r] + bias_n;
    }
  }
}

extern "C" void kernel_launch(void* const* d_in, const int* in_sizes, int n_in,
                              void* d_out, int out_size, void* d_ws, size_t ws_size,
                              hipStream_t stream) {
  const float* x  = (const float*)d_in[0];
  const float* wq = (const float*)d_in[1];
  const float* bq = (const float*)d_in[2];
  const float* wk = (const float*)d_in[3];
  const float* bk = (const float*)d_in[4];
  const float* wv = (const float*)d_in[5];
  const float* bv = (const float*)d_in[6];
  const float* wp = (const float*)d_in[7];
  const float* bp = (const float*)d_in[8];

  float* out_y = (float*)d_out;                       // (B,T,C)
  float* out_k = out_y + (size_t)BB * TT * CC;        // (B,H,T,D)
  float* out_v = out_k + (size_t)BB * HH * TT * DD;   // (B,H,T,D)

  u16* xb  = (u16*)d_ws;                    // B*T*C
  u16* wtq = xb + (size_t)BB * TT * CC;
  u16* wtk = wtq + (size_t)CC * CC;
  u16* wtv = wtk + (size_t)CC * CC;
  u16* wtp = wtv + (size_t)CC * CC;
  u16* qb  = wtp + (size_t)CC * CC;         // (B,H,T,D) bf16
  u16* kb  = qb + (size_t)BB * TT * CC;
  u16* vb  = kb + (size_t)BB * TT * CC;
  u16* yb  = vb + (size_t)BB * TT * CC;     // (B,T,C) bf16

  k_cast_x<<<(BB * TT * CC) / 1024, 256, 0, stream>>>(x, xb);
  k_transpose_w<<<dim3(CC / 32, CC / 32, 4), dim3(32, 8), 0, stream>>>(
      wq, wk, wv, wp, wtq, wtk, wtv, wtp);
  k_gemm_qkv<<<dim3(BB * TT / 64, CC / 64, 3), 256, 0, stream>>>(
      xb, wtq, wtk, wtv, bq, bk, bv, qb, kb, vb, out_k, out_v);
  k_attn<<<dim3(TT / 64, BB * HH), 256, 0, stream>>>(qb, kb, vb, yb);
  k_gemm_proj<<<dim3(BB * TT / 64, CC / 64), 256, 0, stream>>>(yb, wtp, bp, out_y);
}

// Round 2
// 599.438 us; speedup vs baseline: 1.7597x; 1.7597x over previous
//
#include <hip/hip_runtime.h>
#include <hip/hip_bf16.h>
#include <stdint.h>

typedef unsigned short u16;
typedef __bf16 bf16x8 __attribute__((ext_vector_type(8)));
typedef float f32x4 __attribute__((ext_vector_type(4)));

#define BB 4
#define TT 2048
#define CC 1024
#define HH 16
#define DD 64

__device__ __forceinline__ u16 f2bf(float f) {
  union { float f; unsigned int u; } v; v.f = f;
  unsigned int u = v.u;
  unsigned int r = (u + 0x7fffu + ((u >> 16) & 1u)) >> 16;
  return (u16)r;
}

__device__ __forceinline__ void async_copy16(const void* g, void* l) {
  __builtin_amdgcn_global_load_lds(
      (const __attribute__((address_space(1))) void*)g,
      (__attribute__((address_space(3))) void*)l, 16, 0, 0);
}

// ---------------- cast x -> bf16 ----------------
__global__ __launch_bounds__(256) void k_cast_x(const float* __restrict__ x,
                                                u16* __restrict__ xb) {
  int i = (blockIdx.x * 256 + threadIdx.x) * 4;
  float4 f = *reinterpret_cast<const float4*>(x + i);
  ushort4 o;
  o.x = f2bf(f.x); o.y = f2bf(f.y); o.z = f2bf(f.z); o.w = f2bf(f.w);
  *reinterpret_cast<ushort4*>(xb + i) = o;
}

// ------------- transpose + cast weights: wt[n][k] = w[k][n] -------------
__global__ __launch_bounds__(256) void k_transpose_w(
    const float* __restrict__ w0, const float* __restrict__ w1,
    const float* __restrict__ w2, const float* __restrict__ w3,
    u16* __restrict__ t0, u16* __restrict__ t1,
    u16* __restrict__ t2, u16* __restrict__ t3) {
  const float* w = blockIdx.z == 0 ? w0 : blockIdx.z == 1 ? w1 : blockIdx.z == 2 ? w2 : w3;
  u16* t = blockIdx.z == 0 ? t0 : blockIdx.z == 1 ? t1 : blockIdx.z == 2 ? t2 : t3;
  __shared__ u16 tile[32][33];
  int tx = threadIdx.x, ty = threadIdx.y;
  int k0 = blockIdx.x * 32, n0 = blockIdx.y * 32;
#pragma unroll
  for (int r = 0; r < 4; r++)
    tile[ty + r * 8][tx] = f2bf(w[(size_t)(k0 + ty + r * 8) * CC + n0 + tx]);
  __syncthreads();
#pragma unroll
  for (int r = 0; r < 4; r++)
    t[(size_t)(n0 + ty + r * 8) * CC + k0 + tx] = tile[tx][ty + r * 8];
}

// ---------------- m97-structure GEMM core ----------------
// 128x128 tile, BK=32, 4 waves (2x2), each wave 64x64 via 4x4 x (16x16x32).
// A: row-major [M][K] bf16 (xb / yb). B: transposed weights wt[n][k] bf16.
// LDS tiles row-major [128][32] (64B rows = 4 x 16B chunks) — layout matches
// global_load_lds's wave-uniform-base + lane*16 requirement.

#define GEMM_PROLOGUE()                                                        \
  int tid = threadIdx.x;                                                       \
  int lane = tid & 63;                                                         \
  int wave = tid >> 6;                                                         \
  int l15 = lane & 15, quad = lane >> 4;                                       \
  int wave_m = wave & 1, wave_n = wave >> 1;                                   \
  __shared__ u16 lA[128 * 32];                                                 \
  __shared__ u16 lB[128 * 32];                                                 \
  f32x4 acc[4][4] = {};                                                        \
  for (int k0 = 0; k0 < CC; k0 += 32) {                                        \
    __syncthreads();                                                           \
    _Pragma("unroll")                                                          \
    for (int r = 0; r < 2; r++) {                                              \
      int c = r * 256 + tid;                                                   \
      int row = c >> 2, col8 = (c & 3) * 8;                                    \
      async_copy16(A + (size_t)(tile_m + row) * CC + k0 + col8, &lA[c * 8]);   \
    }                                                                          \
    _Pragma("unroll")                                                          \
    for (int r = 0; r < 2; r++) {                                              \
      int c = r * 256 + tid;                                                   \
      int row = c >> 2, col8 = (c & 3) * 8;                                    \
      async_copy16(Bt + (size_t)(tile_n + row) * CC + k0 + col8, &lB[c * 8]);  \
    }                                                                          \
    __syncthreads();                                                           \
    bf16x8 af[4], bfr[4];                                                      \
    _Pragma("unroll")                                                          \
    for (int i = 0; i < 4; i++)                                                \
      af[i] = *reinterpret_cast<const bf16x8*>(                                \
          &lA[(wave_m * 64 + i * 16 + l15) * 32 + quad * 8]);                  \
    _Pragma("unroll")                                                          \
    for (int j = 0; j < 4; j++)                                                \
      bfr[j] = *reinterpret_cast<const bf16x8*>(                               \
          &lB[(wave_n * 64 + j * 16 + l15) * 32 + quad * 8]);                  \
    _Pragma("unroll")                                                          \
    for (int i = 0; i < 4; i++)                                                \
      _Pragma("unroll")                                                        \
      for (int j = 0; j < 4; j++)                                              \
        acc[i][j] =                                                            \
            __builtin_amdgcn_mfma_f32_16x16x32_bf16(af[i], bfr[j], acc[i][j],  \
                                                    0, 0, 0);                  \
  }

// ---------------- fused QKV GEMM ----------------
// mat 0 -> q (bf16 ws), 1 -> k (fp32 out + bf16 ws), 2 -> v (fp32 out + bf16 ws)
__global__ __launch_bounds__(256) void k_gemm_qkv(
    const u16* __restrict__ xb,
    const u16* __restrict__ wtq, const u16* __restrict__ wtk, const u16* __restrict__ wtv,
    const float* __restrict__ bq, const float* __restrict__ bk, const float* __restrict__ bv,
    u16* __restrict__ qb, u16* __restrict__ kb, u16* __restrict__ vb,
    float* __restrict__ out_k, float* __restrict__ out_v) {
  int mat = blockIdx.z;
  const u16* A = xb;
  const u16* Bt = mat == 0 ? wtq : mat == 1 ? wtk : wtv;
  const float* bias = mat == 0 ? bq : mat == 1 ? bk : bv;
  int tile_m = blockIdx.x * 128;
  int tile_n = blockIdx.y * 128;

  GEMM_PROLOGUE()

#pragma unroll
  for (int j = 0; j < 4; j++) {
    int n = tile_n + wave_n * 64 + j * 16 + l15;
    int h = n >> 6, d = n & 63;
    float bias_n = bias[n];
#pragma unroll
    for (int i = 0; i < 4; i++) {
#pragma unroll
      for (int r = 0; r < 4; r++) {
        int m = tile_m + wave_m * 64 + i * 16 + quad * 4 + r;
        int b = m >> 11, t = m & 2047;
        float val = acc[i][j][r] + bias_n;
        size_t idx = (((size_t)(b * HH + h)) * TT + t) * DD + d;
        if (mat == 0) {
          qb[idx] = f2bf(val);
        } else if (mat == 1) {
          out_k[idx] = val;
          kb[idx] = f2bf(val);
        } else {
          out_v[idx] = val;
          vb[idx] = f2bf(val);
        }
      }
    }
  }
}

// ---------------- output projection ----------------
__global__ __launch_bounds__(256) void k_gemm_proj(
    const u16* __restrict__ yb, const u16* __restrict__ wtp,
    const float* __restrict__ bp, float* __restrict__ out) {
  const u16* A = yb;
  const u16* Bt = wtp;
  int tile_m = blockIdx.x * 128;
  int tile_n = blockIdx.y * 128;

  GEMM_PROLOGUE()

#pragma unroll
  for (int j = 0; j < 4; j++) {
    int n = tile_n + wave_n * 64 + j * 16 + l15;
    float bias_n = bp[n];
#pragma unroll
    for (int i = 0; i < 4; i++) {
#pragma unroll
      for (int r = 0; r < 4; r++) {
        int m = tile_m + wave_m * 64 + i * 16 + quad * 4 + r;
        out[(size_t)m * CC + n] = acc[i][j][r] + bias_n;
      }
    }
  }
}

// ---------------- flash attention (causal) ----------------
// grid: (T/64, B*H), block 256 (4 waves, 16 query rows per wave)
__global__ __launch_bounds__(256) void k_attn(
    const u16* __restrict__ qb, const u16* __restrict__ kbuf, const u16* __restrict__ vbuf,
    u16* __restrict__ yatt) {
  int qblk = blockIdx.x;
  int bh = blockIdx.y;
  int tid = threadIdx.x;
  int lane = tid & 63;
  int wave = tid >> 6;
  int l15 = lane & 15, quad = lane >> 4;

  const u16* Q = qb + (size_t)bh * TT * DD;
  const u16* K = kbuf + (size_t)bh * TT * DD;
  const u16* V = vbuf + (size_t)bh * TT * DD;

  __shared__ u16 vt[64][72];      // [d][key] transposed V tile
  __shared__ u16 pl[4][16][72];   // [wave][qrow][key] P tile

  int qr = qblk * 64 + wave * 16 + l15;
  bf16x8 qf0 = *reinterpret_cast<const bf16x8*>(Q + (size_t)qr * DD + quad * 8);
  bf16x8 qf1 = *reinterpret_cast<const bf16x8*>(Q + (size_t)qr * DD + 32 + quad * 8);

  f32x4 o_acc[4] = {};
  float m_run[4], l_run[4];
#pragma unroll
  for (int r = 0; r < 4; r++) { m_run[r] = -1e30f; l_run[r] = 0.f; }

  for (int kblk = 0; kblk <= qblk; kblk++) {
    __syncthreads();
    // stage V^T tile: vt[d][key] = V[kblk*64+key][d]
#pragma unroll
    for (int rep = 0; rep < 16; rep++) {
      int idx = rep * 256 + tid;
      int key = idx >> 6, d = idx & 63;
      vt[d][key] = V[(size_t)(kblk * 64 + key) * DD + d];
    }
    __syncthreads();

    // S = Q K^T (16 rows x 64 keys per wave)
    f32x4 s_acc[4];
#pragma unroll
    for (int nb = 0; nb < 4; nb++) {
      int key = kblk * 64 + nb * 16 + l15;
      bf16x8 kf0 = *reinterpret_cast<const bf16x8*>(K + (size_t)key * DD + quad * 8);
      bf16x8 kf1 = *reinterpret_cast<const bf16x8*>(K + (size_t)key * DD + 32 + quad * 8);
      f32x4 z = {};
      z = __builtin_amdgcn_mfma_f32_16x16x32_bf16(qf0, kf0, z, 0, 0, 0);
      z = __builtin_amdgcn_mfma_f32_16x16x32_bf16(qf1, kf1, z, 0, 0, 0);
      s_acc[nb] = z;
    }

    // mask + row max
    float p[4][4];   // [nb][r]
    float newm[4];
#pragma unroll
    for (int r = 0; r < 4; r++) {
      int qg = qblk * 64 + wave * 16 + quad * 4 + r;
      float mx = -1e30f;
#pragma unroll
      for (int nb = 0; nb < 4; nb++) {
        int kg = kblk * 64 + nb * 16 + l15;
        float s = s_acc[nb][r] * 0.125f;
        s = (kg <= qg) ? s : -1e30f;
        p[nb][r] = s;
        mx = fmaxf(mx, s);
      }
      newm[r] = mx;
    }
#pragma unroll
    for (int off = 1; off < 16; off <<= 1) {
#pragma unroll
      for (int r = 0; r < 4; r++)
        newm[r] = fmaxf(newm[r], __shfl_xor(newm[r], off, 64));
    }

    float alpha[4], rs[4];
#pragma unroll
    for (int r = 0; r < 4; r++) {
      float mnew = fmaxf(m_run[r], newm[r]);
      alpha[r] = __expf(m_run[r] - mnew);
      m_run[r] = mnew;
      float local = 0.f;
#pragma unroll
      for (int nb = 0; nb < 4; nb++) {
        float e = __expf(p[nb][r] - mnew);
        p[nb][r] = e;
        local += e;
      }
      rs[r] = local;
    }
#pragma unroll
    for (int off = 1; off < 16; off <<= 1) {
#pragma unroll
      for (int r = 0; r < 4; r++)
        rs[r] += __shfl_xor(rs[r], off, 64);
    }
#pragma unroll
    for (int r = 0; r < 4; r++) {
      l_run[r] = l_run[r] * alpha[r] + rs[r];
#pragma unroll
      for (int db = 0; db < 4; db++) o_acc[db][r] *= alpha[r];
    }

    // P -> LDS (C-layout -> row major)
#pragma unroll
    for (int nb = 0; nb < 4; nb++)
#pragma unroll
      for (int r = 0; r < 4; r++)
        pl[wave][quad * 4 + r][nb * 16 + l15] = f2bf(p[nb][r]);
    __syncthreads();

    // O += P V
#pragma unroll
    for (int half = 0; half < 2; half++) {
      bf16x8 pf = *reinterpret_cast<const bf16x8*>(&pl[wave][l15][half * 32 + quad * 8]);
#pragma unroll
      for (int db = 0; db < 4; db++) {
        bf16x8 vf = *reinterpret_cast<const bf16x8*>(&vt[db * 16 + l15][half * 32 + quad * 8]);
        o_acc[db] = __builtin_amdgcn_mfma_f32_16x16x32_bf16(pf, vf, o_acc[db], 0, 0, 0);
      }
    }
  }

  // epilogue: y_att[b][t][h*64+d] bf16
  int h = bh & 15, b = bh >> 4;
#pragma unroll
  for (int r = 0; r < 4; r++) {
    float inv = 1.0f / l_run[r];
    int tq = qblk * 64 + wave * 16 + quad * 4 + r;
#pragma unroll
    for (int db = 0; db < 4; db++) {
      int d = db * 16 + l15;
      yatt[((size_t)(b * TT + tq)) * CC + h * DD + d] = f2bf(o_acc[db][r] * inv);
    }
  }
}

extern "C" void kernel_launch(void* const* d_in, const int* in_sizes, int n_in,
                              void* d_out, int out_size, void* d_ws, size_t ws_size,
                              hipStream_t stream) {
  const float* x  = (const float*)d_in[0];
  const float* wq = (const float*)d_in[1];
  const float* bq = (const float*)d_in[2];
  const float* wk = (const float*)d_in[3];
  const float* bk = (const float*)d_in[4];
  const float* wv = (const float*)d_in[5];
  const float* bv = (const float*)d_in[6];
  const float* wp = (const float*)d_in[7];
  const float* bp = (const float*)d_in[8];

  float* out_y = (float*)d_out;                       // (B,T,C)
  float* out_k = out_y + (size_t)BB * TT * CC;        // (B,H,T,D)
  float* out_v = out_k + (size_t)BB * HH * TT * DD;   // (B,H,T,D)

  u16* xb  = (u16*)d_ws;                    // B*T*C
  u16* wtq = xb + (size_t)BB * TT * CC;
  u16* wtk = wtq + (size_t)CC * CC;
  u16* wtv = wtk + (size_t)CC * CC;
  u16* wtp = wtv + (size_t)CC * CC;
  u16* qb  = wtp + (size_t)CC * CC;         // (B,H,T,D) bf16
  u16* kb  = qb + (size_t)BB * TT * CC;
  u16* vb  = kb + (size_t)BB * TT * CC;
  u16* yb  = vb + (size_t)BB * TT * CC;     // (B,T,C) bf16

  k_cast_x<<<(BB * TT * CC) / 1024, 256, 0, stream>>>(x, xb);
  k_transpose_w<<<dim3(CC / 32, CC / 32, 4), dim3(32, 8), 0, stream>>>(
      wq, wk, wv, wp, wtq, wtk, wtv, wtp);
  k_gemm_qkv<<<dim3(BB * TT / 128, CC / 128, 3), 256, 0, stream>>>(
      xb, wtq, wtk, wtv, bq, bk, bv, qb, kb, vb, out_k, out_v);
  k_attn<<<dim3(TT / 64, BB * HH), 256, 0, stream>>>(qb, kb, vb, yb);
  k_gemm_proj<<<dim3(BB * TT / 128, CC / 128), 256, 0, stream>>>(yb, wtp, bp, out_y);
}

// Round 3
// 535.963 us; speedup vs baseline: 1.9681x; 1.1184x over previous
//
#include <hip/hip_runtime.h>
#include <hip/hip_bf16.h>
#include <stdint.h>

typedef unsigned short u16;
typedef __bf16 bf16x8 __attribute__((ext_vector_type(8)));
typedef float f32x4 __attribute__((ext_vector_type(4)));

#define BB 4
#define TT 2048
#define CC 1024
#define HH 16
#define DD 64

__device__ __forceinline__ u16 f2bf(float f) {
  union { float f; unsigned int u; } v; v.f = f;
  unsigned int u = v.u;
  unsigned int r = (u + 0x7fffu + ((u >> 16) & 1u)) >> 16;
  return (u16)r;
}

__device__ __forceinline__ void async_copy16(const void* g, void* l) {
  __builtin_amdgcn_global_load_lds(
      (const __attribute__((address_space(1))) void*)g,
      (__attribute__((address_space(3))) void*)l, 16, 0, 0);
}

// ---------------- cast x -> bf16 ----------------
__global__ __launch_bounds__(256) void k_cast_x(const float* __restrict__ x,
                                                u16* __restrict__ xb) {
  int i = (blockIdx.x * 256 + threadIdx.x) * 4;
  float4 f = *reinterpret_cast<const float4*>(x + i);
  ushort4 o;
  o.x = f2bf(f.x); o.y = f2bf(f.y); o.z = f2bf(f.z); o.w = f2bf(f.w);
  *reinterpret_cast<ushort4*>(xb + i) = o;
}

// ------------- transpose + cast weights: wt[n][k] = w[k][n] -------------
__global__ __launch_bounds__(256) void k_transpose_w(
    const float* __restrict__ w0, const float* __restrict__ w1,
    const float* __restrict__ w2, const float* __restrict__ w3,
    u16* __restrict__ t0, u16* __restrict__ t1,
    u16* __restrict__ t2, u16* __restrict__ t3) {
  const float* w = blockIdx.z == 0 ? w0 : blockIdx.z == 1 ? w1 : blockIdx.z == 2 ? w2 : w3;
  u16* t = blockIdx.z == 0 ? t0 : blockIdx.z == 1 ? t1 : blockIdx.z == 2 ? t2 : t3;
  __shared__ u16 tile[32][33];
  int tx = threadIdx.x, ty = threadIdx.y;
  int k0 = blockIdx.x * 32, n0 = blockIdx.y * 32;
#pragma unroll
  for (int r = 0; r < 4; r++)
    tile[ty + r * 8][tx] = f2bf(w[(size_t)(k0 + ty + r * 8) * CC + n0 + tx]);
  __syncthreads();
#pragma unroll
  for (int r = 0; r < 4; r++)
    t[(size_t)(n0 + ty + r * 8) * CC + k0 + tx] = tile[tx][ty + r * 8];
}

// ------------- transpose V: out_v fp32 (B,H,T,D) -> vbt bf16 (B,H,D,T) -------------
// grid (T/64, B*H), block 256
__global__ __launch_bounds__(256) void k_transpose_v(
    const float* __restrict__ out_v, u16* __restrict__ vbt) {
  int tb = blockIdx.x * 64;
  int bh = blockIdx.y;
  const float* src = out_v + (size_t)bh * TT * DD;
  u16* dst = vbt + (size_t)bh * TT * DD;
  __shared__ u16 tile[64][65];
  int tid = threadIdx.x;
#pragma unroll
  for (int p = 0; p < 4; p++) {
    int c = p * 256 + tid;           // 1024 chunks of 4 floats
    int t = c >> 4, d0 = (c & 15) * 4;
    float4 f = *reinterpret_cast<const float4*>(src + (size_t)(tb + t) * DD + d0);
    tile[t][d0 + 0] = f2bf(f.x);
    tile[t][d0 + 1] = f2bf(f.y);
    tile[t][d0 + 2] = f2bf(f.z);
    tile[t][d0 + 3] = f2bf(f.w);
  }
  __syncthreads();
#pragma unroll
  for (int p = 0; p < 2; p++) {
    int c = p * 256 + tid;           // 512 chunks of 8 u16
    int d = c >> 3, t0 = (c & 7) * 8;
    ushort4 lo, hi;
    lo.x = tile[t0 + 0][d]; lo.y = tile[t0 + 1][d];
    lo.z = tile[t0 + 2][d]; lo.w = tile[t0 + 3][d];
    hi.x = tile[t0 + 4][d]; hi.y = tile[t0 + 5][d];
    hi.z = tile[t0 + 6][d]; hi.w = tile[t0 + 7][d];
    u16* o = dst + (size_t)d * TT + tb + t0;
    *reinterpret_cast<ushort4*>(o) = lo;
    *reinterpret_cast<ushort4*>(o + 4) = hi;
  }
}

// ---------------- m97-structure GEMM core ----------------
#define GEMM_PROLOGUE()                                                        \
  int tid = threadIdx.x;                                                       \
  int lane = tid & 63;                                                         \
  int wave = tid >> 6;                                                         \
  int l15 = lane & 15, quad = lane >> 4;                                       \
  int wave_m = wave & 1, wave_n = wave >> 1;                                   \
  __shared__ u16 lA[128 * 32];                                                 \
  __shared__ u16 lB[128 * 32];                                                 \
  f32x4 acc[4][4] = {};                                                        \
  for (int k0 = 0; k0 < CC; k0 += 32) {                                        \
    __syncthreads();                                                           \
    _Pragma("unroll")                                                          \
    for (int r = 0; r < 2; r++) {                                              \
      int c = r * 256 + tid;                                                   \
      int row = c >> 2, col8 = (c & 3) * 8;                                    \
      async_copy16(A + (size_t)(tile_m + row) * CC + k0 + col8, &lA[c * 8]);   \
    }                                                                          \
    _Pragma("unroll")                                                          \
    for (int r = 0; r < 2; r++) {                                              \
      int c = r * 256 + tid;                                                   \
      int row = c >> 2, col8 = (c & 3) * 8;                                    \
      async_copy16(Bt + (size_t)(tile_n + row) * CC + k0 + col8, &lB[c * 8]);  \
    }                                                                          \
    __syncthreads();                                                           \
    bf16x8 af[4], bfr[4];                                                      \
    _Pragma("unroll")                                                          \
    for (int i = 0; i < 4; i++)                                                \
      af[i] = *reinterpret_cast<const bf16x8*>(                                \
          &lA[(wave_m * 64 + i * 16 + l15) * 32 + quad * 8]);                  \
    _Pragma("unroll")                                                          \
    for (int j = 0; j < 4; j++)                                                \
      bfr[j] = *reinterpret_cast<const bf16x8*>(                               \
          &lB[(wave_n * 64 + j * 16 + l15) * 32 + quad * 8]);                  \
    _Pragma("unroll")                                                          \
    for (int i = 0; i < 4; i++)                                                \
      _Pragma("unroll")                                                        \
      for (int j = 0; j < 4; j++)                                              \
        acc[i][j] =                                                            \
            __builtin_amdgcn_mfma_f32_16x16x32_bf16(af[i], bfr[j], acc[i][j],  \
                                                    0, 0, 0);                  \
  }

// ---------------- fused QKV GEMM ----------------
__global__ __launch_bounds__(256) void k_gemm_qkv(
    const u16* __restrict__ xb,
    const u16* __restrict__ wtq, const u16* __restrict__ wtk, const u16* __restrict__ wtv,
    const float* __restrict__ bq, const float* __restrict__ bk, const float* __restrict__ bv,
    u16* __restrict__ qb, u16* __restrict__ kb,
    float* __restrict__ out_k, float* __restrict__ out_v) {
  int mat = blockIdx.z;
  const u16* A = xb;
  const u16* Bt = mat == 0 ? wtq : mat == 1 ? wtk : wtv;
  const float* bias = mat == 0 ? bq : mat == 1 ? bk : bv;
  int tile_m = blockIdx.x * 128;
  int tile_n = blockIdx.y * 128;

  GEMM_PROLOGUE()

#pragma unroll
  for (int j = 0; j < 4; j++) {
    int n = tile_n + wave_n * 64 + j * 16 + l15;
    int h = n >> 6, d = n & 63;
    float bias_n = bias[n];
#pragma unroll
    for (int i = 0; i < 4; i++) {
#pragma unroll
      for (int r = 0; r < 4; r++) {
        int m = tile_m + wave_m * 64 + i * 16 + quad * 4 + r;
        int b = m >> 11, t = m & 2047;
        float val = acc[i][j][r] + bias_n;
        size_t idx = (((size_t)(b * HH + h)) * TT + t) * DD + d;
        if (mat == 0) {
          qb[idx] = f2bf(val);
        } else if (mat == 1) {
          out_k[idx] = val;
          kb[idx] = f2bf(val);
        } else {
          out_v[idx] = val;
        }
      }
    }
  }
}

// ---------------- output projection ----------------
__global__ __launch_bounds__(256) void k_gemm_proj(
    const u16* __restrict__ yb, const u16* __restrict__ wtp,
    const float* __restrict__ bp, float* __restrict__ out) {
  const u16* A = yb;
  const u16* Bt = wtp;
  int tile_m = blockIdx.x * 128;
  int tile_n = blockIdx.y * 128;

  GEMM_PROLOGUE()

#pragma unroll
  for (int j = 0; j < 4; j++) {
    int n = tile_n + wave_n * 64 + j * 16 + l15;
    float bias_n = bp[n];
#pragma unroll
    for (int i = 0; i < 4; i++) {
#pragma unroll
      for (int r = 0; r < 4; r++) {
        int m = tile_m + wave_m * 64 + i * 16 + quad * 4 + r;
        out[(size_t)m * CC + n] = acc[i][j][r] + bias_n;
      }
    }
  }
}

// ---------------- flash attention (causal), barrier-free k-loop ----------------
// grid: (16, B*H), block 256 (4 waves, 16 q-rows per wave).
// Each block processes q-tiles qpair and 31-qpair -> uniform 33 iterations.
// K fragments + V^T fragments load directly from global (L1/L2-resident tiles).
// Only LDS use: per-wave P round-trip (no __syncthreads in the k-loop).
__global__ __launch_bounds__(256) void k_attn(
    const u16* __restrict__ qb, const u16* __restrict__ kbuf,
    const u16* __restrict__ vtb, u16* __restrict__ yatt) {
  int qpair = blockIdx.x;
  int bh = blockIdx.y;
  int tid = threadIdx.x;
  int lane = tid & 63;
  int wave = tid >> 6;
  int l15 = lane & 15, quad = lane >> 4;

  const u16* Q = qb + (size_t)bh * TT * DD;
  const u16* K = kbuf + (size_t)bh * TT * DD;
  const u16* Vt = vtb + (size_t)bh * TT * DD;  // [d][t]

  __shared__ u16 pl[4][16][72];  // per-wave P tile [qrow][key]

  int h = bh & 15, b = bh >> 4;

#pragma unroll
  for (int side = 0; side < 2; side++) {
    int qt = side == 0 ? qpair : 31 - qpair;

    int qr = qt * 64 + wave * 16 + l15;
    bf16x8 qf0 = *reinterpret_cast<const bf16x8*>(Q + (size_t)qr * DD + quad * 8);
    bf16x8 qf1 = *reinterpret_cast<const bf16x8*>(Q + (size_t)qr * DD + 32 + quad * 8);

    f32x4 o_acc[4] = {};
    float m_run[4], l_run[4];
#pragma unroll
    for (int r = 0; r < 4; r++) { m_run[r] = -1e30f; l_run[r] = 0.f; }

    for (int kblk = 0; kblk <= qt; kblk++) {
      // ---- S = Q K^T (16 rows x 64 keys per wave) ----
      f32x4 s_acc[4];
#pragma unroll
      for (int nb = 0; nb < 4; nb++) {
        const u16* kp = K + (size_t)(kblk * 64 + nb * 16 + l15) * DD + quad * 8;
        bf16x8 kf0 = *reinterpret_cast<const bf16x8*>(kp);
        bf16x8 kf1 = *reinterpret_cast<const bf16x8*>(kp + 32);
        f32x4 z = {};
        z = __builtin_amdgcn_mfma_f32_16x16x32_bf16(qf0, kf0, z, 0, 0, 0);
        z = __builtin_amdgcn_mfma_f32_16x16x32_bf16(qf1, kf1, z, 0, 0, 0);
        s_acc[nb] = z;
      }

      // ---- mask (diagonal block only) + row max ----
      float p[4][4];
      float newm[4];
      if (kblk == qt) {
#pragma unroll
        for (int r = 0; r < 4; r++) {
          int qg = qt * 64 + wave * 16 + quad * 4 + r;
          float mx = -1e30f;
#pragma unroll
          for (int nb = 0; nb < 4; nb++) {
            int kg = kblk * 64 + nb * 16 + l15;
            float s = s_acc[nb][r] * 0.125f;
            s = (kg <= qg) ? s : -1e30f;
            p[nb][r] = s;
            mx = fmaxf(mx, s);
          }
          newm[r] = mx;
        }
      } else {
#pragma unroll
        for (int r = 0; r < 4; r++) {
          float mx = -1e30f;
#pragma unroll
          for (int nb = 0; nb < 4; nb++) {
            float s = s_acc[nb][r] * 0.125f;
            p[nb][r] = s;
            mx = fmaxf(mx, s);
          }
          newm[r] = mx;
        }
      }
#pragma unroll
      for (int off = 1; off < 16; off <<= 1) {
#pragma unroll
        for (int r = 0; r < 4; r++)
          newm[r] = fmaxf(newm[r], __shfl_xor(newm[r], off, 64));
      }

      float alpha[4], rs[4];
#pragma unroll
      for (int r = 0; r < 4; r++) {
        float mnew = fmaxf(m_run[r], newm[r]);
        alpha[r] = __expf(m_run[r] - mnew);
        m_run[r] = mnew;
        float local = 0.f;
#pragma unroll
        for (int nb = 0; nb < 4; nb++) {
          float e = __expf(p[nb][r] - mnew);
          p[nb][r] = e;
          local += e;
        }
        rs[r] = local;
      }
#pragma unroll
      for (int off = 1; off < 16; off <<= 1) {
#pragma unroll
        for (int r = 0; r < 4; r++)
          rs[r] += __shfl_xor(rs[r], off, 64);
      }
#pragma unroll
      for (int r = 0; r < 4; r++) {
        l_run[r] = l_run[r] * alpha[r] + rs[r];
#pragma unroll
        for (int db = 0; db < 4; db++) o_acc[db][r] *= alpha[r];
      }

      // ---- P: C-layout -> A-layout via per-wave LDS (no barrier needed) ----
#pragma unroll
      for (int nb = 0; nb < 4; nb++)
#pragma unroll
        for (int r = 0; r < 4; r++)
          pl[wave][quad * 4 + r][nb * 16 + l15] = f2bf(p[nb][r]);

      // ---- O += P V  (V^T fragments straight from global) ----
#pragma unroll
      for (int half = 0; half < 2; half++) {
        bf16x8 pf = *reinterpret_cast<const bf16x8*>(&pl[wave][l15][half * 32 + quad * 8]);
#pragma unroll
        for (int db = 0; db < 4; db++) {
          bf16x8 vf = *reinterpret_cast<const bf16x8*>(
              Vt + (size_t)(db * 16 + l15) * TT + kblk * 64 + half * 32 + quad * 8);
          o_acc[db] = __builtin_amdgcn_mfma_f32_16x16x32_bf16(pf, vf, o_acc[db], 0, 0, 0);
        }
      }
    }

    // ---- epilogue: y_att[b][t][h*64+d] bf16 ----
#pragma unroll
    for (int r = 0; r < 4; r++) {
      float inv = 1.0f / l_run[r];
      int tq = qt * 64 + wave * 16 + quad * 4 + r;
#pragma unroll
      for (int db = 0; db < 4; db++) {
        int d = db * 16 + l15;
        yatt[((size_t)(b * TT + tq)) * CC + h * DD + d] = f2bf(o_acc[db][r] * inv);
      }
    }
  }
}

extern "C" void kernel_launch(void* const* d_in, const int* in_sizes, int n_in,
                              void* d_out, int out_size, void* d_ws, size_t ws_size,
                              hipStream_t stream) {
  const float* x  = (const float*)d_in[0];
  const float* wq = (const float*)d_in[1];
  const float* bq = (const float*)d_in[2];
  const float* wk = (const float*)d_in[3];
  const float* bk = (const float*)d_in[4];
  const float* wv = (const float*)d_in[5];
  const float* bv = (const float*)d_in[6];
  const float* wp = (const float*)d_in[7];
  const float* bp = (const float*)d_in[8];

  float* out_y = (float*)d_out;                       // (B,T,C)
  float* out_k = out_y + (size_t)BB * TT * CC;        // (B,H,T,D)
  float* out_v = out_k + (size_t)BB * HH * TT * DD;   // (B,H,T,D)

  u16* xb  = (u16*)d_ws;                    // B*T*C
  u16* wtq = xb + (size_t)BB * TT * CC;
  u16* wtk = wtq + (size_t)CC * CC;
  u16* wtv = wtk + (size_t)CC * CC;
  u16* wtp = wtv + (size_t)CC * CC;
  u16* qb  = wtp + (size_t)CC * CC;         // (B,H,T,D) bf16
  u16* kb  = qb + (size_t)BB * TT * CC;     // (B,H,T,D) bf16
  u16* vbt = kb + (size_t)BB * TT * CC;     // (B,H,D,T) bf16
  u16* yb  = vbt + (size_t)BB * TT * CC;    // (B,T,C) bf16

  k_cast_x<<<(BB * TT * CC) / 1024, 256, 0, stream>>>(x, xb);
  k_transpose_w<<<dim3(CC / 32, CC / 32, 4), dim3(32, 8), 0, stream>>>(
      wq, wk, wv, wp, wtq, wtk, wtv, wtp);
  k_gemm_qkv<<<dim3(BB * TT / 128, CC / 128, 3), 256, 0, stream>>>(
      xb, wtq, wtk, wtv, bq, bk, bv, qb, kb, out_k, out_v);
  k_transpose_v<<<dim3(TT / 64, BB * HH), 256, 0, stream>>>(out_v, vbt);
  k_attn<<<dim3(16, BB * HH), 256, 0, stream>>>(qb, kb, vbt, yb);
  k_gemm_proj<<<dim3(BB * TT / 128, CC / 128), 256, 0, stream>>>(yb, wtp, bp, out_y);
}